// Round 24
// baseline (218.093 us; speedup 1.0000x reference)
//
#include <hip/hip_runtime.h>
#include <hip/hip_bf16.h>
#include <math.h>

// Round 24: occupancy test, single change -- (256,4) -> (256,5).
//  r23 (zero-barrier pairs) was neutral: residual stall is L1 staging
//  latency x TLP. LDS 30.7KB and VGPR 60 both permit 5 blocks/CU; only the
//  launch bound caps us at 4. r21's (256,5) regression was confounded with
//  de-coalesced staging; r23's tid-striped staging isolates occupancy.

#define NB 65536
#define SPB 24

typedef __attribute__((ext_vector_type(8))) short short8;
typedef __attribute__((ext_vector_type(4))) float f32x4;

__device__ __forceinline__ unsigned bfr(float f) {
    unsigned u = __float_as_uint(f);
    return (u + 0x7fffu + ((u >> 16) & 1u)) >> 16;
}
__device__ __forceinline__ unsigned pack_bf(float a, float b) {
    return bfr(a) | (bfr(b) << 16);
}
__device__ __forceinline__ float bf_lo(unsigned u) { return __uint_as_float(u << 16); }
__device__ __forceinline__ float bf_hi(unsigned u) { return __uint_as_float(u & 0xffff0000u); }

__global__ __launch_bounds__(256, 5) void fused_all(
    const float* __restrict__ x,
    const float* __restrict__ h_w1, const float* __restrict__ h_b1,
    const float* __restrict__ h_w2, const float* __restrict__ h_b2,
    const float* __restrict__ h_w3, const float* __restrict__ h_b3,
    const float* __restrict__ c_w1, const float* __restrict__ c_b1,
    const float* __restrict__ c_w2, const float* __restrict__ c_b2,
    const float* __restrict__ c_w3, const float* __restrict__ c_b3,
    const float* __restrict__ t_w1, const float* __restrict__ t_b1,
    const float* __restrict__ t_w2, const float* __restrict__ t_b2,
    const float* __restrict__ t_w3, const float* __restrict__ t_b3,
    const float* __restrict__ f_w1, const float* __restrict__ f_b1,
    const float* __restrict__ f_w2, const float* __restrict__ f_b2,
    const float* __restrict__ f_w3, const float* __restrict__ f_b3,
    float* __restrict__ out)
{
    // [0,4800)    acts u16 [240][40] (x / h1 / h2 / ho / u|v); later sT f32 [24][33]
    // [4800,7680) h1p u16 [240][24]; sC f32 stride-12 alias; later team
    //             staging u16 [48][104]
    __shared__ unsigned smem_u[7680];
    unsigned short* const acts = (unsigned short*)smem_u;
    unsigned* const h1pU = smem_u + 4800;
    unsigned short* const h1pU16 = (unsigned short*)(smem_u + 4800);
    float* const sC = (float*)(smem_u + 4800);              // stride 12 f32
    unsigned short* const tmS = (unsigned short*)(smem_u + 4800);  // team staging
    float* const sT = (float*)smem_u;                        // [24][33] f32

    const int tid = threadIdx.x;
    const int s0  = blockIdx.x * SPB;
    const int vs  = (NB - s0 < SPB) ? (NB - s0) : SPB;
    const int vr  = vs * 10;

    const int lane = tid & 63;
    const int wv   = tid >> 6;
    const int lm   = lane & 15;
    const int lg   = lane >> 4;
    const short8 zero8 = (short8){0,0,0,0,0,0,0,0};

    // ==== hero L1: [240x140]@[140x32], tid-striped staging ====
    f32x4 acc[4][2];
    #pragma unroll
    for (int t = 0; t < 4; ++t) {
        const float b0 = h_b1[lm], b1 = h_b1[16 + lm];
        acc[t][0] = (f32x4){b0, b0, b0, b0};
        acc[t][1] = (f32x4){b1, b1, b1, b1};
    }
    for (int c = 0; c < 5; ++c) {
        short8 w0f, w1f;
        #pragma unroll
        for (int i = 0; i < 8; ++i) {
            const int k = c * 32 + lg * 8 + i;
            w0f[i] = (short)((k < 140) ? bfr(h_w1[k * 32 + lm]) : 0);
            w1f[i] = (short)((k < 140) ? bfr(h_w1[k * 32 + 16 + lm]) : 0);
        }
        for (int j = tid; j < vr * 8; j += 256) {
            const int row = j >> 3, q = j & 7;
            unsigned lo = 0, hi = 0;
            if (c < 4 || q < 3) {
                const float4 v = *(const float4*)(
                    x + ((size_t)s0 * 10 + row) * 140 + c * 32 + q * 4);
                lo = pack_bf(v.x, v.y);
                hi = pack_bf(v.z, v.w);
            }
            smem_u[row * 20 + q * 2]     = lo;
            smem_u[row * 20 + q * 2 + 1] = hi;
        }
        __syncthreads();
        #pragma unroll
        for (int t = 0; t < 4; ++t) {
            const int tl = wv + 4 * t;
            if (tl < 15) {
                const short8 af = *(const short8*)(acts + (tl * 16 + lm) * 40 + lg * 8);
                acc[t][0] = __builtin_amdgcn_mfma_f32_16x16x32_bf16(af, w0f, acc[t][0], 0, 0, 0);
                acc[t][1] = __builtin_amdgcn_mfma_f32_16x16x32_bf16(af, w1f, acc[t][1], 0, 0, 0);
            }
        }
        __syncthreads();
    }
    // h1 relu -> own tiles (wave-private)
    #pragma unroll
    for (int t = 0; t < 4; ++t) {
        const int tl = wv + 4 * t;
        if (tl < 15) {
            #pragma unroll
            for (int nt = 0; nt < 2; ++nt)
                #pragma unroll
                for (int r = 0; r < 4; ++r)
                    acts[(tl * 16 + lg * 4 + r) * 40 + nt * 16 + lm] =
                        (unsigned short)bfr(fmaxf(acc[t][nt][r], 0.f));
        }
    }

    // ==== hero L2: wave-private, in-place ====
    {
        short8 af[4];
        #pragma unroll
        for (int t = 0; t < 4; ++t) {
            const int tl = wv + 4 * t;
            af[t] = (tl < 15) ? *(const short8*)(acts + (tl * 16 + lm) * 40 + lg * 8) : zero8;
        }
        short8 w0f, w1f;
        #pragma unroll
        for (int i = 0; i < 8; ++i) {
            const int k = lg * 8 + i;
            w0f[i] = (short)bfr(h_w2[k * 32 + lm]);
            w1f[i] = (short)bfr(h_w2[k * 32 + 16 + lm]);
        }
        #pragma unroll
        for (int t = 0; t < 4; ++t) {
            const float b0 = h_b2[lm], b1 = h_b2[16 + lm];
            f32x4 a20 = (f32x4){b0, b0, b0, b0};
            f32x4 a21 = (f32x4){b1, b1, b1, b1};
            const int tl = wv + 4 * t;
            if (tl < 15) {
                a20 = __builtin_amdgcn_mfma_f32_16x16x32_bf16(af[t], w0f, a20, 0, 0, 0);
                a21 = __builtin_amdgcn_mfma_f32_16x16x32_bf16(af[t], w1f, a21, 0, 0, 0);
                #pragma unroll
                for (int r = 0; r < 4; ++r) {
                    acts[(tl * 16 + lg * 4 + r) * 40 + lm]      =
                        (unsigned short)bfr(fmaxf(a20[r], 0.f));
                    acts[(tl * 16 + lg * 4 + r) * 40 + 16 + lm] =
                        (unsigned short)bfr(fmaxf(a21[r], 0.f));
                }
            }
        }
    }

    // ==== hero L3 -> acts cols 0..15 AND horeg (packed) ====
    unsigned horeg[4][2];
    {
        short8 af[4];
        #pragma unroll
        for (int t = 0; t < 4; ++t) {
            const int tl = wv + 4 * t;
            af[t] = (tl < 15) ? *(const short8*)(acts + (tl * 16 + lm) * 40 + lg * 8) : zero8;
        }
        short8 w3f;
        #pragma unroll
        for (int i = 0; i < 8; ++i)
            w3f[i] = (short)bfr(h_w3[(lg * 8 + i) * 16 + lm]);
        #pragma unroll
        for (int t = 0; t < 4; ++t) {
            const float b = h_b3[lm];
            f32x4 a3 = (f32x4){b, b, b, b};
            const int tl = wv + 4 * t;
            horeg[t][0] = 0; horeg[t][1] = 0;
            if (tl < 15) {
                a3 = __builtin_amdgcn_mfma_f32_16x16x32_bf16(af[t], w3f, a3, 0, 0, 0);
                #pragma unroll
                for (int r = 0; r < 4; ++r)
                    acts[(tl * 16 + lg * 4 + r) * 40 + lm] = (unsigned short)bfr(a3[r]);
                horeg[t][0] = pack_bf(a3[0], a3[1]);
                horeg[t][1] = pack_bf(a3[2], a3[3]);
            }
        }
    }

    // ==== uv via MFMA (wave-private) ====
    {
        short8 af[4];
        #pragma unroll
        for (int t = 0; t < 4; ++t) {
            const int tl = wv + 4 * t;
            af[t] = (tl < 15 && lg < 2)
                ? *(const short8*)(acts + (tl * 16 + lm) * 40 + lg * 8) : zero8;
        }
        short8 wuf, wvf;
        #pragma unroll
        for (int i = 0; i < 8; ++i) {
            const int k = lg * 8 + i;
            wuf[i] = (short)((k < 16) ? bfr(c_w1[k * 16 + lm]) : 0);
            wvf[i] = (short)((k < 16) ? bfr(c_w1[(16 + k) * 16 + lm]) : 0);
        }
        #pragma unroll
        for (int t = 0; t < 4; ++t) {
            const int tl = wv + 4 * t;
            if (tl < 15) {
                f32x4 au = (f32x4){0.f, 0.f, 0.f, 0.f};
                f32x4 av = (f32x4){0.f, 0.f, 0.f, 0.f};
                au = __builtin_amdgcn_mfma_f32_16x16x32_bf16(af[t], wuf, au, 0, 0, 0);
                av = __builtin_amdgcn_mfma_f32_16x16x32_bf16(af[t], wvf, av, 0, 0, 0);
                #pragma unroll
                for (int r = 0; r < 4; ++r) {
                    const int row = tl * 16 + lg * 4 + r;
                    acts[row * 40 + lm]      = (unsigned short)bfr(au[r]);
                    acts[row * 40 + 16 + lm] = (unsigned short)bfr(av[r]);
                }
            }
        }
    }
    __syncthreads();                 // u/v visible block-wide

    // ==== counter pairs: 5 passes, ZERO barriers (fully wave-private) ====
    float m00 = -1e30f, m01 = -1e30f, m02 = -1e30f, m03 = -1e30f;
    float m10 = -1e30f, m11 = -1e30f, m12 = -1e30f, m13 = -1e30f;
    short8 cw2f, cw3f;
    #pragma unroll
    for (int i = 0; i < 8; ++i) {
        const int k = lg * 8 + i;
        cw2f[i] = (short)((k < 16) ? bfr(c_w2[k * 16 + lm]) : 0);
        cw3f[i] = (short)((k < 16 && lm < 8) ? bfr(c_w3[k * 8 + lm]) : 0);
    }
    const int btl  = wv + 4 * lg;          // lane's build/pool tile
    const int prow = btl * 16 + lm;        // lane's row
    const int pt10 = prow % 10;            // row's sample-local pair idx
    for (int p = 0; p < 5; ++p) {
        if (btl < 15 && prow < vr) {
            const int s = prow / 10;
            const int pr = p * 10 + pt10;
            int i, j;
            if (pr < 25) { i = pr / 5; j = 5 + pr % 5; }
            else { const int q = pr - 25; i = 5 + q / 5; j = q % 5; }
            const unsigned* ur  = smem_u + (s * 10 + i) * 20;
            const unsigned* vr2 = smem_u + (s * 10 + j) * 20 + 8;
            #pragma unroll
            for (int cc = 0; cc < 8; ++cc) {
                const unsigned uu = ur[cc], vv = vr2[cc];
                const float a = fmaxf(bf_lo(uu) + bf_lo(vv) + c_b1[2 * cc], 0.f);
                const float b = fmaxf(bf_hi(uu) + bf_hi(vv) + c_b1[2 * cc + 1], 0.f);
                h1pU[prow * 12 + cc] = pack_bf(a, b);
            }
        }
        #pragma unroll
        for (int t = 0; t < 4; ++t) {
            const int tl = wv + 4 * t;
            if (tl < 15) {
                const short8 af2 = (lg < 2)
                    ? *(const short8*)(h1pU16 + (tl * 16 + lm) * 24 + lg * 8) : zero8;
                const float b2 = c_b2[lm];
                f32x4 a2 = (f32x4){b2, b2, b2, b2};
                a2 = __builtin_amdgcn_mfma_f32_16x16x32_bf16(af2, cw2f, a2, 0, 0, 0);
                #pragma unroll
                for (int r = 0; r < 4; ++r)
                    h1pU16[(tl * 16 + lg * 4 + r) * 24 + lm] =
                        (unsigned short)bfr(fmaxf(a2[r], 0.f));
                const short8 af3 = (lg < 2)
                    ? *(const short8*)(h1pU16 + (tl * 16 + lm) * 24 + lg * 8) : zero8;
                const float b3 = (lm < 8) ? c_b3[lm] : 0.f;
                f32x4 a3 = (f32x4){b3, b3, b3, b3};
                a3 = __builtin_amdgcn_mfma_f32_16x16x32_bf16(af3, cw3f, a3, 0, 0, 0);
                if (lm < 8) {
                    #pragma unroll
                    for (int r = 0; r < 4; ++r)
                        sC[(tl * 16 + lg * 4 + r) * 12 + lm] = a3[r];
                }
            }
        }
        if (btl < 15 && prow < vr) {
            const float* cr = sC + prow * 12;
            const float p0 = fmaxf(cr[0], cr[1]);
            const float p1 = fmaxf(cr[2], cr[3]);
            const float p2 = fmaxf(cr[4], cr[5]);
            const float p3 = fmaxf(cr[6], cr[7]);
            const int pr = p * 10 + pt10;
            if (pr < 25) {
                m00 = fmaxf(m00, p0); m01 = fmaxf(m01, p1);
                m02 = fmaxf(m02, p2); m03 = fmaxf(m03, p3);
            } else {
                m10 = fmaxf(m10, p0); m11 = fmaxf(m11, p1);
                m12 = fmaxf(m12, p2); m13 = fmaxf(m13, p3);
            }
        }
    }

    // ==== stage per-row maxima -> barrier -> cross-wave reduce ====
    if (btl < 15 && prow < vr) {
        float* dst = sC + prow * 12;
        dst[0] = m00; dst[1] = m01; dst[2] = m02; dst[3] = m03;
        dst[4] = m10; dst[5] = m11; dst[6] = m12; dst[7] = m13;
    }
    __syncthreads();
    float gval = 0.f;
    if (tid < vs * 8) {
        const int s = tid >> 3, r = tid & 7;
        float mx = -1e30f;
        #pragma unroll
        for (int t = 0; t < 10; ++t)
            mx = fmaxf(mx, sC[(s * 10 + t) * 12 + r]);
        gval = mx;
    }
    __syncthreads();                 // sC reads done before team staging

    // ==== team staging [48][104]u16 over dead h1p/sC region ====
    for (int j = tid; j < 48 * 6; j += 256) {
        const int row = j / 6, q = 46 + j % 6;
        ((unsigned*)tmS)[row * 52 + q] = 0;
    }
    for (int j = tid; j < 48 * 4; j += 256) {
        const int row = j / 4, q = 42 + j % 4;
        ((unsigned*)tmS)[row * 52 + q] = 0;
    }
    #pragma unroll
    for (int t = 0; t < 4; ++t) {
        const int tl = wv + 4 * t;
        if (tl < 15) {
            #pragma unroll
            for (int r = 0; r < 4; ++r) {
                const int grow = tl * 16 + lg * 4 + r;
                if (grow < vr) {
                    const int s = grow / 10, h = grow % 10;
                    const int tr = s * 2 + (h >= 5);
                    const int col = (h % 5) * 16 + lm;
                    const unsigned pk = horeg[t][r >> 1];
                    const unsigned short hv = (unsigned short)((r & 1) ? (pk >> 16) : (pk & 0xffff));
                    tmS[tr * 104 + col] = hv;
                }
            }
        }
    }
    if (tid < vs * 8) {
        const int s = tid >> 3, r = tid & 7;
        const int tr = s * 2 + (r >> 2);
        tmS[tr * 104 + 80 + (r & 3)] = (unsigned short)bfr(gval);
    }
    __syncthreads();

    // ==== team MFMA chain: 48 rows = 3 tiles, waves 0..2 ====
    if (wv < 3) {
        f32x4 a1[4];
        #pragma unroll
        for (int nt = 0; nt < 4; ++nt) {
            const float b = t_b1[nt * 16 + lm];
            a1[nt] = (f32x4){b, b, b, b};
        }
        for (int c = 0; c < 3; ++c) {
            const short8 af = *(const short8*)(tmS + (wv * 16 + lm) * 104 + c * 32 + lg * 8);
            #pragma unroll
            for (int nt = 0; nt < 4; ++nt) {
                short8 wf;
                #pragma unroll
                for (int i = 0; i < 8; ++i) {
                    const int k = c * 32 + lg * 8 + i;
                    wf[i] = (short)((k < 84) ? bfr(t_w1[k * 64 + nt * 16 + lm]) : 0);
                }
                a1[nt] = __builtin_amdgcn_mfma_f32_16x16x32_bf16(af, wf, a1[nt], 0, 0, 0);
            }
        }
        #pragma unroll
        for (int nt = 0; nt < 4; ++nt)
            #pragma unroll
            for (int r = 0; r < 4; ++r)
                tmS[(wv * 16 + lg * 4 + r) * 104 + nt * 16 + lm] =
                    (unsigned short)bfr(fmaxf(a1[nt][r], 0.f));

        f32x4 a2[4];
        #pragma unroll
        for (int nt = 0; nt < 4; ++nt) {
            const float b = t_b2[nt * 16 + lm];
            a2[nt] = (f32x4){b, b, b, b};
        }
        for (int c = 0; c < 2; ++c) {
            const short8 af = *(const short8*)(tmS + (wv * 16 + lm) * 104 + c * 32 + lg * 8);
            #pragma unroll
            for (int nt = 0; nt < 4; ++nt) {
                short8 wf;
                #pragma unroll
                for (int i = 0; i < 8; ++i) {
                    const int k = c * 32 + lg * 8 + i;
                    wf[i] = (short)bfr(t_w2[k * 64 + nt * 16 + lm]);
                }
                a2[nt] = __builtin_amdgcn_mfma_f32_16x16x32_bf16(af, wf, a2[nt], 0, 0, 0);
            }
        }
        #pragma unroll
        for (int nt = 0; nt < 4; ++nt)
            #pragma unroll
            for (int r = 0; r < 4; ++r)
                tmS[(wv * 16 + lg * 4 + r) * 104 + nt * 16 + lm] =
                    (unsigned short)bfr(fmaxf(a2[nt][r], 0.f));

        const float b = t_b3[lm];
        f32x4 a3 = (f32x4){b, b, b, b};
        for (int c = 0; c < 2; ++c) {
            const short8 af = *(const short8*)(tmS + (wv * 16 + lm) * 104 + c * 32 + lg * 8);
            short8 wf;
            #pragma unroll
            for (int i = 0; i < 8; ++i) {
                const int k = c * 32 + lg * 8 + i;
                wf[i] = (short)bfr(t_w3[k * 16 + lm]);
            }
            a3 = __builtin_amdgcn_mfma_f32_16x16x32_bf16(af, wf, a3, 0, 0, 0);
        }
        #pragma unroll
        for (int r = 0; r < 4; ++r) {
            const int row = wv * 16 + lg * 4 + r;
            if ((row >> 1) < vs)
                sT[(row >> 1) * 33 + (row & 1) * 16 + lm] = a3[r];
        }
    }
    __syncthreads();

    // ==== final MLP (32->16->16->2) + softmax, 1 lane/sample ====
    if (tid < vs) {
        const float* tr = sT + tid * 33;
        float g1[16];
        #pragma unroll
        for (int o = 0; o < 16; ++o) g1[o] = f_b1[o];
        #pragma unroll
        for (int k = 0; k < 32; ++k) {
            const float hk = tr[k];
            const float* wr = f_w1 + k * 16;
            #pragma unroll
            for (int o = 0; o < 16; ++o) g1[o] = fmaf(hk, wr[o], g1[o]);
        }
        float g2[16];
        #pragma unroll
        for (int o = 0; o < 16; ++o) g2[o] = f_b2[o];
        #pragma unroll
        for (int k = 0; k < 16; ++k) {
            const float hk = fmaxf(g1[k], 0.f);
            const float* wr = f_w2 + k * 16;
            #pragma unroll
            for (int o = 0; o < 16; ++o) g2[o] = fmaf(hk, wr[o], g2[o]);
        }
        float l0 = f_b3[0], l1 = f_b3[1];
        #pragma unroll
        for (int k = 0; k < 16; ++k) {
            const float hk = fmaxf(g2[k], 0.f);
            l0 = fmaf(hk, f_w3[2 * k], l0);
            l1 = fmaf(hk, f_w3[2 * k + 1], l1);
        }
        const float e = expf(l1 - l0);
        const float p0 = 1.f / (1.f + e);
        out[(size_t)(s0 + tid) * 2]     = p0;
        out[(size_t)(s0 + tid) * 2 + 1] = 1.f - p0;
    }
}

extern "C" void kernel_launch(void* const* d_in, const int* in_sizes, int n_in,
                              void* d_out, int out_size, void* d_ws, size_t ws_size,
                              hipStream_t stream) {
    (void)in_sizes; (void)n_in; (void)out_size; (void)d_ws; (void)ws_size;
    const float* x    = (const float*)d_in[0];
    const float* h_w1 = (const float*)d_in[1];  const float* h_b1 = (const float*)d_in[2];
    const float* h_w2 = (const float*)d_in[3];  const float* h_b2 = (const float*)d_in[4];
    const float* h_w3 = (const float*)d_in[5];  const float* h_b3 = (const float*)d_in[6];
    const float* c_w1 = (const float*)d_in[7];  const float* c_b1 = (const float*)d_in[8];
    const float* c_w2 = (const float*)d_in[9];  const float* c_b2 = (const float*)d_in[10];
    const float* c_w3 = (const float*)d_in[11]; const float* c_b3 = (const float*)d_in[12];
    const float* t_w1 = (const float*)d_in[13]; const float* t_b1 = (const float*)d_in[14];
    const float* t_w2 = (const float*)d_in[15]; const float* t_b2 = (const float*)d_in[16];
    const float* t_w3 = (const float*)d_in[17]; const float* t_b3 = (const float*)d_in[18];
    const float* f_w1 = (const float*)d_in[19]; const float* f_b1 = (const float*)d_in[20];
    const float* f_w2 = (const float*)d_in[21]; const float* f_b2 = (const float*)d_in[22];
    const float* f_w3 = (const float*)d_in[23]; const float* f_b3 = (const float*)d_in[24];
    float* out = (float*)d_out;

    const int grid = (NB + SPB - 1) / SPB;    // 2731
    fused_all<<<grid, 256, 0, stream>>>(
        x, h_w1, h_b1, h_w2, h_b2, h_w3, h_b3,
        c_w1, c_b1, c_w2, c_b2, c_w3, c_b3,
        t_w1, t_b1, t_w2, t_b2, t_w3, t_b3,
        f_w1, f_b1, f_w2, f_b2, f_w3, f_b3, out);
}

// Round 25
// 187.341 us; speedup vs baseline: 1.1642x; 1.1642x over previous
//
#include <hip/hip_runtime.h>
#include <hip/hip_bf16.h>
#include <math.h>

// Round 25: direct-from-global L1 A-fragments (delete x staging).
//  r24 falsified occupancy (5th spill-by-launch-bounds). r23 base (193us)
//  is latency-bound in the L1 staging loop (10 block barriers + LDS round
//  trip). The L1 A-frag is 8 CONTIGUOUS floats of one x row -> load as two
//  aligned float4 from global, cvt to bf16 in regs. Removes all L1 barriers
//  (front of kernel to uv now barrier-free), ~500 staging VALU ops/lane,
//  and the LDS x round-trip. Line utilization stays 100% (lg pairs share
//  64B lines). Launch bounds back to (256,4).

#define NB 65536
#define SPB 24

typedef __attribute__((ext_vector_type(8))) short short8;
typedef __attribute__((ext_vector_type(4))) float f32x4;

__device__ __forceinline__ unsigned bfr(float f) {
    unsigned u = __float_as_uint(f);
    return (u + 0x7fffu + ((u >> 16) & 1u)) >> 16;
}
__device__ __forceinline__ unsigned pack_bf(float a, float b) {
    return bfr(a) | (bfr(b) << 16);
}
__device__ __forceinline__ float bf_lo(unsigned u) { return __uint_as_float(u << 16); }
__device__ __forceinline__ float bf_hi(unsigned u) { return __uint_as_float(u & 0xffff0000u); }

__global__ __launch_bounds__(256, 4) void fused_all(
    const float* __restrict__ x,
    const float* __restrict__ h_w1, const float* __restrict__ h_b1,
    const float* __restrict__ h_w2, const float* __restrict__ h_b2,
    const float* __restrict__ h_w3, const float* __restrict__ h_b3,
    const float* __restrict__ c_w1, const float* __restrict__ c_b1,
    const float* __restrict__ c_w2, const float* __restrict__ c_b2,
    const float* __restrict__ c_w3, const float* __restrict__ c_b3,
    const float* __restrict__ t_w1, const float* __restrict__ t_b1,
    const float* __restrict__ t_w2, const float* __restrict__ t_b2,
    const float* __restrict__ t_w3, const float* __restrict__ t_b3,
    const float* __restrict__ f_w1, const float* __restrict__ f_b1,
    const float* __restrict__ f_w2, const float* __restrict__ f_b2,
    const float* __restrict__ f_w3, const float* __restrict__ f_b3,
    float* __restrict__ out)
{
    // [0,4800)    acts u16 [240][40] (h1 / h2 / ho / u|v); later sT f32 [24][33]
    // [4800,7680) h1p u16 [240][24]; sC f32 stride-12 alias; later team
    //             staging u16 [48][104]
    __shared__ unsigned smem_u[7680];
    unsigned short* const acts = (unsigned short*)smem_u;
    unsigned* const h1pU = smem_u + 4800;
    unsigned short* const h1pU16 = (unsigned short*)(smem_u + 4800);
    float* const sC = (float*)(smem_u + 4800);              // stride 12 f32
    unsigned short* const tmS = (unsigned short*)(smem_u + 4800);  // team staging
    float* const sT = (float*)smem_u;                        // [24][33] f32

    const int tid = threadIdx.x;
    const int s0  = blockIdx.x * SPB;
    const int vs  = (NB - s0 < SPB) ? (NB - s0) : SPB;
    const int vr  = vs * 10;

    const int lane = tid & 63;
    const int wv   = tid >> 6;
    const int lm   = lane & 15;
    const int lg   = lane >> 4;
    const short8 zero8 = (short8){0,0,0,0,0,0,0,0};

    // ==== hero L1: [240x140]@[140x32], A-frags DIRECT from global ====
    f32x4 acc[4][2];
    #pragma unroll
    for (int t = 0; t < 4; ++t) {
        const float b0 = h_b1[lm], b1 = h_b1[16 + lm];
        acc[t][0] = (f32x4){b0, b0, b0, b0};
        acc[t][1] = (f32x4){b1, b1, b1, b1};
    }
    for (int c = 0; c < 4; ++c) {          // full chunks: k = c*32 .. c*32+31
        short8 w0f, w1f;
        #pragma unroll
        for (int i = 0; i < 8; ++i) {
            const int k = c * 32 + lg * 8 + i;
            w0f[i] = (short)bfr(h_w1[k * 32 + lm]);
            w1f[i] = (short)bfr(h_w1[k * 32 + 16 + lm]);
        }
        #pragma unroll
        for (int t = 0; t < 4; ++t) {
            const int tl = wv + 4 * t;
            const int row = tl * 16 + lm;
            short8 af = zero8;
            if (tl < 15 && row < vr) {
                const float* xr = x + ((size_t)s0 * 10 + row) * 140 + c * 32 + lg * 8;
                const float4 v0 = *(const float4*)xr;        // 16B aligned (560|128|32)
                const float4 v1 = *(const float4*)(xr + 4);
                af[0] = (short)bfr(v0.x); af[1] = (short)bfr(v0.y);
                af[2] = (short)bfr(v0.z); af[3] = (short)bfr(v0.w);
                af[4] = (short)bfr(v1.x); af[5] = (short)bfr(v1.y);
                af[6] = (short)bfr(v1.z); af[7] = (short)bfr(v1.w);
            }
            if (tl < 15) {
                acc[t][0] = __builtin_amdgcn_mfma_f32_16x16x32_bf16(af, w0f, acc[t][0], 0, 0, 0);
                acc[t][1] = __builtin_amdgcn_mfma_f32_16x16x32_bf16(af, w1f, acc[t][1], 0, 0, 0);
            }
        }
    }
    {   // tail chunk c=4: k = 128..139 valid (12)
        short8 w0f, w1f;
        #pragma unroll
        for (int i = 0; i < 8; ++i) {
            const int k = 128 + lg * 8 + i;
            w0f[i] = (short)((k < 140) ? bfr(h_w1[k * 32 + lm]) : 0);
            w1f[i] = (short)((k < 140) ? bfr(h_w1[k * 32 + 16 + lm]) : 0);
        }
        #pragma unroll
        for (int t = 0; t < 4; ++t) {
            const int tl = wv + 4 * t;
            const int row = tl * 16 + lm;
            short8 af = zero8;
            if (tl < 15 && row < vr && lg < 2) {
                const float* xr = x + ((size_t)s0 * 10 + row) * 140 + 128 + lg * 8;
                const float4 v0 = *(const float4*)xr;        // k..k+3 (valid both lg)
                af[0] = (short)bfr(v0.x); af[1] = (short)bfr(v0.y);
                af[2] = (short)bfr(v0.z); af[3] = (short)bfr(v0.w);
                if (lg == 0) {                                // k=132..135
                    const float4 v1 = *(const float4*)(xr + 4);
                    af[4] = (short)bfr(v1.x); af[5] = (short)bfr(v1.y);
                    af[6] = (short)bfr(v1.z); af[7] = (short)bfr(v1.w);
                }
            }
            if (tl < 15) {
                acc[t][0] = __builtin_amdgcn_mfma_f32_16x16x32_bf16(af, w0f, acc[t][0], 0, 0, 0);
                acc[t][1] = __builtin_amdgcn_mfma_f32_16x16x32_bf16(af, w1f, acc[t][1], 0, 0, 0);
            }
        }
    }
    // h1 relu -> own tiles (wave-private)
    #pragma unroll
    for (int t = 0; t < 4; ++t) {
        const int tl = wv + 4 * t;
        if (tl < 15) {
            #pragma unroll
            for (int nt = 0; nt < 2; ++nt)
                #pragma unroll
                for (int r = 0; r < 4; ++r)
                    acts[(tl * 16 + lg * 4 + r) * 40 + nt * 16 + lm] =
                        (unsigned short)bfr(fmaxf(acc[t][nt][r], 0.f));
        }
    }

    // ==== hero L2: wave-private, in-place ====
    {
        short8 af[4];
        #pragma unroll
        for (int t = 0; t < 4; ++t) {
            const int tl = wv + 4 * t;
            af[t] = (tl < 15) ? *(const short8*)(acts + (tl * 16 + lm) * 40 + lg * 8) : zero8;
        }
        short8 w0f, w1f;
        #pragma unroll
        for (int i = 0; i < 8; ++i) {
            const int k = lg * 8 + i;
            w0f[i] = (short)bfr(h_w2[k * 32 + lm]);
            w1f[i] = (short)bfr(h_w2[k * 32 + 16 + lm]);
        }
        #pragma unroll
        for (int t = 0; t < 4; ++t) {
            const float b0 = h_b2[lm], b1 = h_b2[16 + lm];
            f32x4 a20 = (f32x4){b0, b0, b0, b0};
            f32x4 a21 = (f32x4){b1, b1, b1, b1};
            const int tl = wv + 4 * t;
            if (tl < 15) {
                a20 = __builtin_amdgcn_mfma_f32_16x16x32_bf16(af[t], w0f, a20, 0, 0, 0);
                a21 = __builtin_amdgcn_mfma_f32_16x16x32_bf16(af[t], w1f, a21, 0, 0, 0);
                #pragma unroll
                for (int r = 0; r < 4; ++r) {
                    acts[(tl * 16 + lg * 4 + r) * 40 + lm]      =
                        (unsigned short)bfr(fmaxf(a20[r], 0.f));
                    acts[(tl * 16 + lg * 4 + r) * 40 + 16 + lm] =
                        (unsigned short)bfr(fmaxf(a21[r], 0.f));
                }
            }
        }
    }

    // ==== hero L3 -> acts cols 0..15 AND horeg (packed) ====
    unsigned horeg[4][2];
    {
        short8 af[4];
        #pragma unroll
        for (int t = 0; t < 4; ++t) {
            const int tl = wv + 4 * t;
            af[t] = (tl < 15) ? *(const short8*)(acts + (tl * 16 + lm) * 40 + lg * 8) : zero8;
        }
        short8 w3f;
        #pragma unroll
        for (int i = 0; i < 8; ++i)
            w3f[i] = (short)bfr(h_w3[(lg * 8 + i) * 16 + lm]);
        #pragma unroll
        for (int t = 0; t < 4; ++t) {
            const float b = h_b3[lm];
            f32x4 a3 = (f32x4){b, b, b, b};
            const int tl = wv + 4 * t;
            horeg[t][0] = 0; horeg[t][1] = 0;
            if (tl < 15) {
                a3 = __builtin_amdgcn_mfma_f32_16x16x32_bf16(af[t], w3f, a3, 0, 0, 0);
                #pragma unroll
                for (int r = 0; r < 4; ++r)
                    acts[(tl * 16 + lg * 4 + r) * 40 + lm] = (unsigned short)bfr(a3[r]);
                horeg[t][0] = pack_bf(a3[0], a3[1]);
                horeg[t][1] = pack_bf(a3[2], a3[3]);
            }
        }
    }

    // ==== uv via MFMA (wave-private) ====
    {
        short8 af[4];
        #pragma unroll
        for (int t = 0; t < 4; ++t) {
            const int tl = wv + 4 * t;
            af[t] = (tl < 15 && lg < 2)
                ? *(const short8*)(acts + (tl * 16 + lm) * 40 + lg * 8) : zero8;
        }
        short8 wuf, wvf;
        #pragma unroll
        for (int i = 0; i < 8; ++i) {
            const int k = lg * 8 + i;
            wuf[i] = (short)((k < 16) ? bfr(c_w1[k * 16 + lm]) : 0);
            wvf[i] = (short)((k < 16) ? bfr(c_w1[(16 + k) * 16 + lm]) : 0);
        }
        #pragma unroll
        for (int t = 0; t < 4; ++t) {
            const int tl = wv + 4 * t;
            if (tl < 15) {
                f32x4 au = (f32x4){0.f, 0.f, 0.f, 0.f};
                f32x4 av = (f32x4){0.f, 0.f, 0.f, 0.f};
                au = __builtin_amdgcn_mfma_f32_16x16x32_bf16(af[t], wuf, au, 0, 0, 0);
                av = __builtin_amdgcn_mfma_f32_16x16x32_bf16(af[t], wvf, av, 0, 0, 0);
                #pragma unroll
                for (int r = 0; r < 4; ++r) {
                    const int row = tl * 16 + lg * 4 + r;
                    acts[row * 40 + lm]      = (unsigned short)bfr(au[r]);
                    acts[row * 40 + 16 + lm] = (unsigned short)bfr(av[r]);
                }
            }
        }
    }
    __syncthreads();                 // u/v visible block-wide

    // ==== counter pairs: 5 passes, zero barriers (wave-private, r23) ====
    float m00 = -1e30f, m01 = -1e30f, m02 = -1e30f, m03 = -1e30f;
    float m10 = -1e30f, m11 = -1e30f, m12 = -1e30f, m13 = -1e30f;
    short8 cw2f, cw3f;
    #pragma unroll
    for (int i = 0; i < 8; ++i) {
        const int k = lg * 8 + i;
        cw2f[i] = (short)((k < 16) ? bfr(c_w2[k * 16 + lm]) : 0);
        cw3f[i] = (short)((k < 16 && lm < 8) ? bfr(c_w3[k * 8 + lm]) : 0);
    }
    const int btl  = wv + 4 * lg;
    const int prow = btl * 16 + lm;
    const int pt10 = prow % 10;
    for (int p = 0; p < 5; ++p) {
        if (btl < 15 && prow < vr) {
            const int s = prow / 10;
            const int pr = p * 10 + pt10;
            int i, j;
            if (pr < 25) { i = pr / 5; j = 5 + pr % 5; }
            else { const int q = pr - 25; i = 5 + q / 5; j = q % 5; }
            const unsigned* ur  = smem_u + (s * 10 + i) * 20;
            const unsigned* vr2 = smem_u + (s * 10 + j) * 20 + 8;
            #pragma unroll
            for (int cc = 0; cc < 8; ++cc) {
                const unsigned uu = ur[cc], vv = vr2[cc];
                const float a = fmaxf(bf_lo(uu) + bf_lo(vv) + c_b1[2 * cc], 0.f);
                const float b = fmaxf(bf_hi(uu) + bf_hi(vv) + c_b1[2 * cc + 1], 0.f);
                h1pU[prow * 12 + cc] = pack_bf(a, b);
            }
        }
        #pragma unroll
        for (int t = 0; t < 4; ++t) {
            const int tl = wv + 4 * t;
            if (tl < 15) {
                const short8 af2 = (lg < 2)
                    ? *(const short8*)(h1pU16 + (tl * 16 + lm) * 24 + lg * 8) : zero8;
                const float b2 = c_b2[lm];
                f32x4 a2 = (f32x4){b2, b2, b2, b2};
                a2 = __builtin_amdgcn_mfma_f32_16x16x32_bf16(af2, cw2f, a2, 0, 0, 0);
                #pragma unroll
                for (int r = 0; r < 4; ++r)
                    h1pU16[(tl * 16 + lg * 4 + r) * 24 + lm] =
                        (unsigned short)bfr(fmaxf(a2[r], 0.f));
                const short8 af3 = (lg < 2)
                    ? *(const short8*)(h1pU16 + (tl * 16 + lm) * 24 + lg * 8) : zero8;
                const float b3 = (lm < 8) ? c_b3[lm] : 0.f;
                f32x4 a3 = (f32x4){b3, b3, b3, b3};
                a3 = __builtin_amdgcn_mfma_f32_16x16x32_bf16(af3, cw3f, a3, 0, 0, 0);
                if (lm < 8) {
                    #pragma unroll
                    for (int r = 0; r < 4; ++r)
                        sC[(tl * 16 + lg * 4 + r) * 12 + lm] = a3[r];
                }
            }
        }
        if (btl < 15 && prow < vr) {
            const float* cr = sC + prow * 12;
            const float p0 = fmaxf(cr[0], cr[1]);
            const float p1 = fmaxf(cr[2], cr[3]);
            const float p2 = fmaxf(cr[4], cr[5]);
            const float p3 = fmaxf(cr[6], cr[7]);
            const int pr = p * 10 + pt10;
            if (pr < 25) {
                m00 = fmaxf(m00, p0); m01 = fmaxf(m01, p1);
                m02 = fmaxf(m02, p2); m03 = fmaxf(m03, p3);
            } else {
                m10 = fmaxf(m10, p0); m11 = fmaxf(m11, p1);
                m12 = fmaxf(m12, p2); m13 = fmaxf(m13, p3);
            }
        }
    }

    // ==== stage per-row maxima -> barrier -> cross-wave reduce ====
    if (btl < 15 && prow < vr) {
        float* dst = sC + prow * 12;
        dst[0] = m00; dst[1] = m01; dst[2] = m02; dst[3] = m03;
        dst[4] = m10; dst[5] = m11; dst[6] = m12; dst[7] = m13;
    }
    __syncthreads();
    float gval = 0.f;
    if (tid < vs * 8) {
        const int s = tid >> 3, r = tid & 7;
        float mx = -1e30f;
        #pragma unroll
        for (int t = 0; t < 10; ++t)
            mx = fmaxf(mx, sC[(s * 10 + t) * 12 + r]);
        gval = mx;
    }
    __syncthreads();                 // sC reads done before team staging

    // ==== team staging [48][104]u16 over dead h1p/sC region ====
    for (int j = tid; j < 48 * 6; j += 256) {
        const int row = j / 6, q = 46 + j % 6;
        ((unsigned*)tmS)[row * 52 + q] = 0;
    }
    for (int j = tid; j < 48 * 4; j += 256) {
        const int row = j / 4, q = 42 + j % 4;
        ((unsigned*)tmS)[row * 52 + q] = 0;
    }
    #pragma unroll
    for (int t = 0; t < 4; ++t) {
        const int tl = wv + 4 * t;
        if (tl < 15) {
            #pragma unroll
            for (int r = 0; r < 4; ++r) {
                const int grow = tl * 16 + lg * 4 + r;
                if (grow < vr) {
                    const int s = grow / 10, h = grow % 10;
                    const int tr = s * 2 + (h >= 5);
                    const int col = (h % 5) * 16 + lm;
                    const unsigned pk = horeg[t][r >> 1];
                    const unsigned short hv = (unsigned short)((r & 1) ? (pk >> 16) : (pk & 0xffff));
                    tmS[tr * 104 + col] = hv;
                }
            }
        }
    }
    if (tid < vs * 8) {
        const int s = tid >> 3, r = tid & 7;
        const int tr = s * 2 + (r >> 2);
        tmS[tr * 104 + 80 + (r & 3)] = (unsigned short)bfr(gval);
    }
    __syncthreads();

    // ==== team MFMA chain: 48 rows = 3 tiles, waves 0..2 ====
    if (wv < 3) {
        f32x4 a1[4];
        #pragma unroll
        for (int nt = 0; nt < 4; ++nt) {
            const float b = t_b1[nt * 16 + lm];
            a1[nt] = (f32x4){b, b, b, b};
        }
        for (int c = 0; c < 3; ++c) {
            const short8 af = *(const short8*)(tmS + (wv * 16 + lm) * 104 + c * 32 + lg * 8);
            #pragma unroll
            for (int nt = 0; nt < 4; ++nt) {
                short8 wf;
                #pragma unroll
                for (int i = 0; i < 8; ++i) {
                    const int k = c * 32 + lg * 8 + i;
                    wf[i] = (short)((k < 84) ? bfr(t_w1[k * 64 + nt * 16 + lm]) : 0);
                }
                a1[nt] = __builtin_amdgcn_mfma_f32_16x16x32_bf16(af, wf, a1[nt], 0, 0, 0);
            }
        }
        #pragma unroll
        for (int nt = 0; nt < 4; ++nt)
            #pragma unroll
            for (int r = 0; r < 4; ++r)
                tmS[(wv * 16 + lg * 4 + r) * 104 + nt * 16 + lm] =
                    (unsigned short)bfr(fmaxf(a1[nt][r], 0.f));

        f32x4 a2[4];
        #pragma unroll
        for (int nt = 0; nt < 4; ++nt) {
            const float b = t_b2[nt * 16 + lm];
            a2[nt] = (f32x4){b, b, b, b};
        }
        for (int c = 0; c < 2; ++c) {
            const short8 af = *(const short8*)(tmS + (wv * 16 + lm) * 104 + c * 32 + lg * 8);
            #pragma unroll
            for (int nt = 0; nt < 4; ++nt) {
                short8 wf;
                #pragma unroll
                for (int i = 0; i < 8; ++i) {
                    const int k = c * 32 + lg * 8 + i;
                    wf[i] = (short)bfr(t_w2[k * 64 + nt * 16 + lm]);
                }
                a2[nt] = __builtin_amdgcn_mfma_f32_16x16x32_bf16(af, wf, a2[nt], 0, 0, 0);
            }
        }
        #pragma unroll
        for (int nt = 0; nt < 4; ++nt)
            #pragma unroll
            for (int r = 0; r < 4; ++r)
                tmS[(wv * 16 + lg * 4 + r) * 104 + nt * 16 + lm] =
                    (unsigned short)bfr(fmaxf(a2[nt][r], 0.f));

        const float b = t_b3[lm];
        f32x4 a3 = (f32x4){b, b, b, b};
        for (int c = 0; c < 2; ++c) {
            const short8 af = *(const short8*)(tmS + (wv * 16 + lm) * 104 + c * 32 + lg * 8);
            short8 wf;
            #pragma unroll
            for (int i = 0; i < 8; ++i) {
                const int k = c * 32 + lg * 8 + i;
                wf[i] = (short)bfr(t_w3[k * 16 + lm]);
            }
            a3 = __builtin_amdgcn_mfma_f32_16x16x32_bf16(af, wf, a3, 0, 0, 0);
        }
        #pragma unroll
        for (int r = 0; r < 4; ++r) {
            const int row = wv * 16 + lg * 4 + r;
            if ((row >> 1) < vs)
                sT[(row >> 1) * 33 + (row & 1) * 16 + lm] = a3[r];
        }
    }
    __syncthreads();

    // ==== final MLP (32->16->16->2) + softmax, 1 lane/sample ====
    if (tid < vs) {
        const float* tr = sT + tid * 33;
        float g1[16];
        #pragma unroll
        for (int o = 0; o < 16; ++o) g1[o] = f_b1[o];
        #pragma unroll
        for (int k = 0; k < 32; ++k) {
            const float hk = tr[k];
            const float* wr = f_w1 + k * 16;
            #pragma unroll
            for (int o = 0; o < 16; ++o) g1[o] = fmaf(hk, wr[o], g1[o]);
        }
        float g2[16];
        #pragma unroll
        for (int o = 0; o < 16; ++o) g2[o] = f_b2[o];
        #pragma unroll
        for (int k = 0; k < 16; ++k) {
            const float hk = fmaxf(g1[k], 0.f);
            const float* wr = f_w2 + k * 16;
            #pragma unroll
            for (int o = 0; o < 16; ++o) g2[o] = fmaf(hk, wr[o], g2[o]);
        }
        float l0 = f_b3[0], l1 = f_b3[1];
        #pragma unroll
        for (int k = 0; k < 16; ++k) {
            const float hk = fmaxf(g2[k], 0.f);
            l0 = fmaf(hk, f_w3[2 * k], l0);
            l1 = fmaf(hk, f_w3[2 * k + 1], l1);
        }
        const float e = expf(l1 - l0);
        const float p0 = 1.f / (1.f + e);
        out[(size_t)(s0 + tid) * 2]     = p0;
        out[(size_t)(s0 + tid) * 2 + 1] = 1.f - p0;
    }
}

extern "C" void kernel_launch(void* const* d_in, const int* in_sizes, int n_in,
                              void* d_out, int out_size, void* d_ws, size_t ws_size,
                              hipStream_t stream) {
    (void)in_sizes; (void)n_in; (void)out_size; (void)d_ws; (void)ws_size;
    const float* x    = (const float*)d_in[0];
    const float* h_w1 = (const float*)d_in[1];  const float* h_b1 = (const float*)d_in[2];
    const float* h_w2 = (const float*)d_in[3];  const float* h_b2 = (const float*)d_in[4];
    const float* h_w3 = (const float*)d_in[5];  const float* h_b3 = (const float*)d_in[6];
    const float* c_w1 = (const float*)d_in[7];  const float* c_b1 = (const float*)d_in[8];
    const float* c_w2 = (const float*)d_in[9];  const float* c_b2 = (const float*)d_in[10];
    const float* c_w3 = (const float*)d_in[11]; const float* c_b3 = (const float*)d_in[12];
    const float* t_w1 = (const float*)d_in[13]; const float* t_b1 = (const float*)d_in[14];
    const float* t_w2 = (const float*)d_in[15]; const float* t_b2 = (const float*)d_in[16];
    const float* t_w3 = (const float*)d_in[17]; const float* t_b3 = (const float*)d_in[18];
    const float* f_w1 = (const float*)d_in[19]; const float* f_b1 = (const float*)d_in[20];
    const float* f_w2 = (const float*)d_in[21]; const float* f_b2 = (const float*)d_in[22];
    const float* f_w3 = (const float*)d_in[23]; const float* f_b3 = (const float*)d_in[24];
    float* out = (float*)d_out;

    const int grid = (NB + SPB - 1) / SPB;    // 2731
    fused_all<<<grid, 256, 0, stream>>>(
        x, h_w1, h_b1, h_w2, h_b2, h_w3, h_b3,
        c_w1, c_b1, c_w2, c_b2, c_w3, c_b3,
        t_w1, t_b1, t_w2, t_b2, t_w3, t_b3,
        f_w1, f_b1, f_w2, f_b2, f_w3, f_b3, out);
}

// Round 26
// 166.085 us; speedup vs baseline: 1.3131x; 1.1280x over previous
//
#include <hip/hip_runtime.h>
#include <hip/hip_bf16.h>
#include <math.h>

// Round 26: one-time bf16 weight pre-conversion (prologue kernel -> d_ws).
//  r25 (187us) is issue/latency-bound; per lane the weight path redoes
//  ~570 scattered 4B gathers + ~1700 VALU of f32->bf16 rounding EVERY
//  block for constant weights. Prologue converts the 9 matmul weight
//  arrays (17408 elems, 35KB) to bf16 once; main kernel gathers 2-byte
//  bf16 directly. Final-MLP weights stay f32 (scalar phase). Numerics
//  identical (same RNE). Body otherwise r25 verbatim.

#define NB 65536
#define SPB 24

// bf16 weight buffer offsets (u16 units)
#define OW_HW1 0
#define OW_HW2 4480
#define OW_HW3 5504
#define OW_CW1 6016
#define OW_CW2 6528
#define OW_CW3 6784
#define OW_TW1 6912
#define OW_TW2 12288
#define OW_TW3 16384
#define OW_TOT 17408

typedef __attribute__((ext_vector_type(8))) short short8;
typedef __attribute__((ext_vector_type(4))) float f32x4;

__device__ __forceinline__ unsigned bfr(float f) {
    unsigned u = __float_as_uint(f);
    return (u + 0x7fffu + ((u >> 16) & 1u)) >> 16;
}
__device__ __forceinline__ unsigned pack_bf(float a, float b) {
    return bfr(a) | (bfr(b) << 16);
}
__device__ __forceinline__ float bf_lo(unsigned u) { return __uint_as_float(u << 16); }
__device__ __forceinline__ float bf_hi(unsigned u) { return __uint_as_float(u & 0xffff0000u); }

__global__ void conv_weights(
    const float* __restrict__ h_w1, const float* __restrict__ h_w2,
    const float* __restrict__ h_w3, const float* __restrict__ c_w1,
    const float* __restrict__ c_w2, const float* __restrict__ c_w3,
    const float* __restrict__ t_w1, const float* __restrict__ t_w2,
    const float* __restrict__ t_w3, unsigned short* __restrict__ wb)
{
    const int i = blockIdx.x * 256 + threadIdx.x;
    if (i >= OW_TOT) return;
    float v;
    if (i < OW_HW2)      v = h_w1[i - OW_HW1];
    else if (i < OW_HW3) v = h_w2[i - OW_HW2];
    else if (i < OW_CW1) v = h_w3[i - OW_HW3];
    else if (i < OW_CW2) v = c_w1[i - OW_CW1];
    else if (i < OW_CW3) v = c_w2[i - OW_CW2];
    else if (i < OW_TW1) v = c_w3[i - OW_CW3];
    else if (i < OW_TW2) v = t_w1[i - OW_TW1];
    else if (i < OW_TW3) v = t_w2[i - OW_TW2];
    else                 v = t_w3[i - OW_TW3];
    wb[i] = (unsigned short)bfr(v);
}

__global__ __launch_bounds__(256, 4) void fused_all(
    const float* __restrict__ x,
    const unsigned short* __restrict__ wb,
    const float* __restrict__ h_b1, const float* __restrict__ h_b2,
    const float* __restrict__ h_b3, const float* __restrict__ c_b1,
    const float* __restrict__ c_b2, const float* __restrict__ c_b3,
    const float* __restrict__ t_b1, const float* __restrict__ t_b2,
    const float* __restrict__ t_b3,
    const float* __restrict__ f_w1, const float* __restrict__ f_b1,
    const float* __restrict__ f_w2, const float* __restrict__ f_b2,
    const float* __restrict__ f_w3, const float* __restrict__ f_b3,
    float* __restrict__ out)
{
    __shared__ unsigned smem_u[7680];
    unsigned short* const acts = (unsigned short*)smem_u;
    unsigned* const h1pU = smem_u + 4800;
    unsigned short* const h1pU16 = (unsigned short*)(smem_u + 4800);
    float* const sC = (float*)(smem_u + 4800);
    unsigned short* const tmS = (unsigned short*)(smem_u + 4800);
    float* const sT = (float*)smem_u;

    const int tid = threadIdx.x;
    const int s0  = blockIdx.x * SPB;
    const int vs  = (NB - s0 < SPB) ? (NB - s0) : SPB;
    const int vr  = vs * 10;

    const int lane = tid & 63;
    const int wv   = tid >> 6;
    const int lm   = lane & 15;
    const int lg   = lane >> 4;
    const short8 zero8 = (short8){0,0,0,0,0,0,0,0};

    // ==== hero L1: [240x140]@[140x32], A-frags DIRECT from global ====
    f32x4 acc[4][2];
    #pragma unroll
    for (int t = 0; t < 4; ++t) {
        const float b0 = h_b1[lm], b1 = h_b1[16 + lm];
        acc[t][0] = (f32x4){b0, b0, b0, b0};
        acc[t][1] = (f32x4){b1, b1, b1, b1};
    }
    for (int c = 0; c < 4; ++c) {
        short8 w0f, w1f;
        #pragma unroll
        for (int i = 0; i < 8; ++i) {
            const int k = c * 32 + lg * 8 + i;
            w0f[i] = (short)wb[OW_HW1 + k * 32 + lm];
            w1f[i] = (short)wb[OW_HW1 + k * 32 + 16 + lm];
        }
        #pragma unroll
        for (int t = 0; t < 4; ++t) {
            const int tl = wv + 4 * t;
            const int row = tl * 16 + lm;
            short8 af = zero8;
            if (tl < 15 && row < vr) {
                const float* xr = x + ((size_t)s0 * 10 + row) * 140 + c * 32 + lg * 8;
                const float4 v0 = *(const float4*)xr;
                const float4 v1 = *(const float4*)(xr + 4);
                af[0] = (short)bfr(v0.x); af[1] = (short)bfr(v0.y);
                af[2] = (short)bfr(v0.z); af[3] = (short)bfr(v0.w);
                af[4] = (short)bfr(v1.x); af[5] = (short)bfr(v1.y);
                af[6] = (short)bfr(v1.z); af[7] = (short)bfr(v1.w);
            }
            if (tl < 15) {
                acc[t][0] = __builtin_amdgcn_mfma_f32_16x16x32_bf16(af, w0f, acc[t][0], 0, 0, 0);
                acc[t][1] = __builtin_amdgcn_mfma_f32_16x16x32_bf16(af, w1f, acc[t][1], 0, 0, 0);
            }
        }
    }
    {   // tail chunk c=4: k = 128..139
        short8 w0f, w1f;
        #pragma unroll
        for (int i = 0; i < 8; ++i) {
            const int k = 128 + lg * 8 + i;
            w0f[i] = (short)((k < 140) ? wb[OW_HW1 + k * 32 + lm] : 0);
            w1f[i] = (short)((k < 140) ? wb[OW_HW1 + k * 32 + 16 + lm] : 0);
        }
        #pragma unroll
        for (int t = 0; t < 4; ++t) {
            const int tl = wv + 4 * t;
            const int row = tl * 16 + lm;
            short8 af = zero8;
            if (tl < 15 && row < vr && lg < 2) {
                const float* xr = x + ((size_t)s0 * 10 + row) * 140 + 128 + lg * 8;
                const float4 v0 = *(const float4*)xr;
                af[0] = (short)bfr(v0.x); af[1] = (short)bfr(v0.y);
                af[2] = (short)bfr(v0.z); af[3] = (short)bfr(v0.w);
                if (lg == 0) {
                    const float4 v1 = *(const float4*)(xr + 4);
                    af[4] = (short)bfr(v1.x); af[5] = (short)bfr(v1.y);
                    af[6] = (short)bfr(v1.z); af[7] = (short)bfr(v1.w);
                }
            }
            if (tl < 15) {
                acc[t][0] = __builtin_amdgcn_mfma_f32_16x16x32_bf16(af, w0f, acc[t][0], 0, 0, 0);
                acc[t][1] = __builtin_amdgcn_mfma_f32_16x16x32_bf16(af, w1f, acc[t][1], 0, 0, 0);
            }
        }
    }
    #pragma unroll
    for (int t = 0; t < 4; ++t) {
        const int tl = wv + 4 * t;
        if (tl < 15) {
            #pragma unroll
            for (int nt = 0; nt < 2; ++nt)
                #pragma unroll
                for (int r = 0; r < 4; ++r)
                    acts[(tl * 16 + lg * 4 + r) * 40 + nt * 16 + lm] =
                        (unsigned short)bfr(fmaxf(acc[t][nt][r], 0.f));
        }
    }

    // ==== hero L2 ====
    {
        short8 af[4];
        #pragma unroll
        for (int t = 0; t < 4; ++t) {
            const int tl = wv + 4 * t;
            af[t] = (tl < 15) ? *(const short8*)(acts + (tl * 16 + lm) * 40 + lg * 8) : zero8;
        }
        short8 w0f, w1f;
        #pragma unroll
        for (int i = 0; i < 8; ++i) {
            const int k = lg * 8 + i;
            w0f[i] = (short)wb[OW_HW2 + k * 32 + lm];
            w1f[i] = (short)wb[OW_HW2 + k * 32 + 16 + lm];
        }
        #pragma unroll
        for (int t = 0; t < 4; ++t) {
            const float b0 = h_b2[lm], b1 = h_b2[16 + lm];
            f32x4 a20 = (f32x4){b0, b0, b0, b0};
            f32x4 a21 = (f32x4){b1, b1, b1, b1};
            const int tl = wv + 4 * t;
            if (tl < 15) {
                a20 = __builtin_amdgcn_mfma_f32_16x16x32_bf16(af[t], w0f, a20, 0, 0, 0);
                a21 = __builtin_amdgcn_mfma_f32_16x16x32_bf16(af[t], w1f, a21, 0, 0, 0);
                #pragma unroll
                for (int r = 0; r < 4; ++r) {
                    acts[(tl * 16 + lg * 4 + r) * 40 + lm]      =
                        (unsigned short)bfr(fmaxf(a20[r], 0.f));
                    acts[(tl * 16 + lg * 4 + r) * 40 + 16 + lm] =
                        (unsigned short)bfr(fmaxf(a21[r], 0.f));
                }
            }
        }
    }

    // ==== hero L3 -> acts cols 0..15 AND horeg ====
    unsigned horeg[4][2];
    {
        short8 af[4];
        #pragma unroll
        for (int t = 0; t < 4; ++t) {
            const int tl = wv + 4 * t;
            af[t] = (tl < 15) ? *(const short8*)(acts + (tl * 16 + lm) * 40 + lg * 8) : zero8;
        }
        short8 w3f;
        #pragma unroll
        for (int i = 0; i < 8; ++i)
            w3f[i] = (short)wb[OW_HW3 + (lg * 8 + i) * 16 + lm];
        #pragma unroll
        for (int t = 0; t < 4; ++t) {
            const float b = h_b3[lm];
            f32x4 a3 = (f32x4){b, b, b, b};
            const int tl = wv + 4 * t;
            horeg[t][0] = 0; horeg[t][1] = 0;
            if (tl < 15) {
                a3 = __builtin_amdgcn_mfma_f32_16x16x32_bf16(af[t], w3f, a3, 0, 0, 0);
                #pragma unroll
                for (int r = 0; r < 4; ++r)
                    acts[(tl * 16 + lg * 4 + r) * 40 + lm] = (unsigned short)bfr(a3[r]);
                horeg[t][0] = pack_bf(a3[0], a3[1]);
                horeg[t][1] = pack_bf(a3[2], a3[3]);
            }
        }
    }

    // ==== uv via MFMA ====
    {
        short8 af[4];
        #pragma unroll
        for (int t = 0; t < 4; ++t) {
            const int tl = wv + 4 * t;
            af[t] = (tl < 15 && lg < 2)
                ? *(const short8*)(acts + (tl * 16 + lm) * 40 + lg * 8) : zero8;
        }
        short8 wuf, wvf;
        #pragma unroll
        for (int i = 0; i < 8; ++i) {
            const int k = lg * 8 + i;
            wuf[i] = (short)((k < 16) ? wb[OW_CW1 + k * 16 + lm] : 0);
            wvf[i] = (short)((k < 16) ? wb[OW_CW1 + (16 + k) * 16 + lm] : 0);
        }
        #pragma unroll
        for (int t = 0; t < 4; ++t) {
            const int tl = wv + 4 * t;
            if (tl < 15) {
                f32x4 au = (f32x4){0.f, 0.f, 0.f, 0.f};
                f32x4 av = (f32x4){0.f, 0.f, 0.f, 0.f};
                au = __builtin_amdgcn_mfma_f32_16x16x32_bf16(af[t], wuf, au, 0, 0, 0);
                av = __builtin_amdgcn_mfma_f32_16x16x32_bf16(af[t], wvf, av, 0, 0, 0);
                #pragma unroll
                for (int r = 0; r < 4; ++r) {
                    const int row = tl * 16 + lg * 4 + r;
                    acts[row * 40 + lm]      = (unsigned short)bfr(au[r]);
                    acts[row * 40 + 16 + lm] = (unsigned short)bfr(av[r]);
                }
            }
        }
    }
    __syncthreads();

    // ==== counter pairs: 5 passes, zero barriers ====
    float m00 = -1e30f, m01 = -1e30f, m02 = -1e30f, m03 = -1e30f;
    float m10 = -1e30f, m11 = -1e30f, m12 = -1e30f, m13 = -1e30f;
    short8 cw2f, cw3f;
    #pragma unroll
    for (int i = 0; i < 8; ++i) {
        const int k = lg * 8 + i;
        cw2f[i] = (short)((k < 16) ? wb[OW_CW2 + k * 16 + lm] : 0);
        cw3f[i] = (short)((k < 16 && lm < 8) ? wb[OW_CW3 + k * 8 + lm] : 0);
    }
    const int btl  = wv + 4 * lg;
    const int prow = btl * 16 + lm;
    const int pt10 = prow % 10;
    for (int p = 0; p < 5; ++p) {
        if (btl < 15 && prow < vr) {
            const int s = prow / 10;
            const int pr = p * 10 + pt10;
            int i, j;
            if (pr < 25) { i = pr / 5; j = 5 + pr % 5; }
            else { const int q = pr - 25; i = 5 + q / 5; j = q % 5; }
            const unsigned* ur  = smem_u + (s * 10 + i) * 20;
            const unsigned* vr2 = smem_u + (s * 10 + j) * 20 + 8;
            #pragma unroll
            for (int cc = 0; cc < 8; ++cc) {
                const unsigned uu = ur[cc], vv = vr2[cc];
                const float a = fmaxf(bf_lo(uu) + bf_lo(vv) + c_b1[2 * cc], 0.f);
                const float b = fmaxf(bf_hi(uu) + bf_hi(vv) + c_b1[2 * cc + 1], 0.f);
                h1pU[prow * 12 + cc] = pack_bf(a, b);
            }
        }
        #pragma unroll
        for (int t = 0; t < 4; ++t) {
            const int tl = wv + 4 * t;
            if (tl < 15) {
                const short8 af2 = (lg < 2)
                    ? *(const short8*)(h1pU16 + (tl * 16 + lm) * 24 + lg * 8) : zero8;
                const float b2 = c_b2[lm];
                f32x4 a2 = (f32x4){b2, b2, b2, b2};
                a2 = __builtin_amdgcn_mfma_f32_16x16x32_bf16(af2, cw2f, a2, 0, 0, 0);
                #pragma unroll
                for (int r = 0; r < 4; ++r)
                    h1pU16[(tl * 16 + lg * 4 + r) * 24 + lm] =
                        (unsigned short)bfr(fmaxf(a2[r], 0.f));
                const short8 af3 = (lg < 2)
                    ? *(const short8*)(h1pU16 + (tl * 16 + lm) * 24 + lg * 8) : zero8;
                const float b3 = (lm < 8) ? c_b3[lm] : 0.f;
                f32x4 a3 = (f32x4){b3, b3, b3, b3};
                a3 = __builtin_amdgcn_mfma_f32_16x16x32_bf16(af3, cw3f, a3, 0, 0, 0);
                if (lm < 8) {
                    #pragma unroll
                    for (int r = 0; r < 4; ++r)
                        sC[(tl * 16 + lg * 4 + r) * 12 + lm] = a3[r];
                }
            }
        }
        if (btl < 15 && prow < vr) {
            const float* cr = sC + prow * 12;
            const float p0 = fmaxf(cr[0], cr[1]);
            const float p1 = fmaxf(cr[2], cr[3]);
            const float p2 = fmaxf(cr[4], cr[5]);
            const float p3 = fmaxf(cr[6], cr[7]);
            const int pr = p * 10 + pt10;
            if (pr < 25) {
                m00 = fmaxf(m00, p0); m01 = fmaxf(m01, p1);
                m02 = fmaxf(m02, p2); m03 = fmaxf(m03, p3);
            } else {
                m10 = fmaxf(m10, p0); m11 = fmaxf(m11, p1);
                m12 = fmaxf(m12, p2); m13 = fmaxf(m13, p3);
            }
        }
    }

    // ==== stage per-row maxima -> barrier -> cross-wave reduce ====
    if (btl < 15 && prow < vr) {
        float* dst = sC + prow * 12;
        dst[0] = m00; dst[1] = m01; dst[2] = m02; dst[3] = m03;
        dst[4] = m10; dst[5] = m11; dst[6] = m12; dst[7] = m13;
    }
    __syncthreads();
    float gval = 0.f;
    if (tid < vs * 8) {
        const int s = tid >> 3, r = tid & 7;
        float mx = -1e30f;
        #pragma unroll
        for (int t = 0; t < 10; ++t)
            mx = fmaxf(mx, sC[(s * 10 + t) * 12 + r]);
        gval = mx;
    }
    __syncthreads();

    // ==== team staging [48][104]u16 ====
    for (int j = tid; j < 48 * 6; j += 256) {
        const int row = j / 6, q = 46 + j % 6;
        ((unsigned*)tmS)[row * 52 + q] = 0;
    }
    for (int j = tid; j < 48 * 4; j += 256) {
        const int row = j / 4, q = 42 + j % 4;
        ((unsigned*)tmS)[row * 52 + q] = 0;
    }
    #pragma unroll
    for (int t = 0; t < 4; ++t) {
        const int tl = wv + 4 * t;
        if (tl < 15) {
            #pragma unroll
            for (int r = 0; r < 4; ++r) {
                const int grow = tl * 16 + lg * 4 + r;
                if (grow < vr) {
                    const int s = grow / 10, h = grow % 10;
                    const int tr = s * 2 + (h >= 5);
                    const int col = (h % 5) * 16 + lm;
                    const unsigned pk = horeg[t][r >> 1];
                    const unsigned short hv = (unsigned short)((r & 1) ? (pk >> 16) : (pk & 0xffff));
                    tmS[tr * 104 + col] = hv;
                }
            }
        }
    }
    if (tid < vs * 8) {
        const int s = tid >> 3, r = tid & 7;
        const int tr = s * 2 + (r >> 2);
        tmS[tr * 104 + 80 + (r & 3)] = (unsigned short)bfr(gval);
    }
    __syncthreads();

    // ==== team MFMA chain: 48 rows = 3 tiles, waves 0..2 ====
    if (wv < 3) {
        f32x4 a1[4];
        #pragma unroll
        for (int nt = 0; nt < 4; ++nt) {
            const float b = t_b1[nt * 16 + lm];
            a1[nt] = (f32x4){b, b, b, b};
        }
        for (int c = 0; c < 3; ++c) {
            const short8 af = *(const short8*)(tmS + (wv * 16 + lm) * 104 + c * 32 + lg * 8);
            #pragma unroll
            for (int nt = 0; nt < 4; ++nt) {
                short8 wf;
                #pragma unroll
                for (int i = 0; i < 8; ++i) {
                    const int k = c * 32 + lg * 8 + i;
                    wf[i] = (short)((k < 84) ? wb[OW_TW1 + k * 64 + nt * 16 + lm] : 0);
                }
                a1[nt] = __builtin_amdgcn_mfma_f32_16x16x32_bf16(af, wf, a1[nt], 0, 0, 0);
            }
        }
        #pragma unroll
        for (int nt = 0; nt < 4; ++nt)
            #pragma unroll
            for (int r = 0; r < 4; ++r)
                tmS[(wv * 16 + lg * 4 + r) * 104 + nt * 16 + lm] =
                    (unsigned short)bfr(fmaxf(a1[nt][r], 0.f));

        f32x4 a2[4];
        #pragma unroll
        for (int nt = 0; nt < 4; ++nt) {
            const float b = t_b2[nt * 16 + lm];
            a2[nt] = (f32x4){b, b, b, b};
        }
        for (int c = 0; c < 2; ++c) {
            const short8 af = *(const short8*)(tmS + (wv * 16 + lm) * 104 + c * 32 + lg * 8);
            #pragma unroll
            for (int nt = 0; nt < 4; ++nt) {
                short8 wf;
                #pragma unroll
                for (int i = 0; i < 8; ++i) {
                    const int k = c * 32 + lg * 8 + i;
                    wf[i] = (short)wb[OW_TW2 + k * 64 + nt * 16 + lm];
                }
                a2[nt] = __builtin_amdgcn_mfma_f32_16x16x32_bf16(af, wf, a2[nt], 0, 0, 0);
            }
        }
        #pragma unroll
        for (int nt = 0; nt < 4; ++nt)
            #pragma unroll
            for (int r = 0; r < 4; ++r)
                tmS[(wv * 16 + lg * 4 + r) * 104 + nt * 16 + lm] =
                    (unsigned short)bfr(fmaxf(a2[nt][r], 0.f));

        const float b = t_b3[lm];
        f32x4 a3 = (f32x4){b, b, b, b};
        for (int c = 0; c < 2; ++c) {
            const short8 af = *(const short8*)(tmS + (wv * 16 + lm) * 104 + c * 32 + lg * 8);
            short8 wf;
            #pragma unroll
            for (int i = 0; i < 8; ++i) {
                const int k = c * 32 + lg * 8 + i;
                wf[i] = (short)wb[OW_TW3 + k * 16 + lm];
            }
            a3 = __builtin_amdgcn_mfma_f32_16x16x32_bf16(af, wf, a3, 0, 0, 0);
        }
        #pragma unroll
        for (int r = 0; r < 4; ++r) {
            const int row = wv * 16 + lg * 4 + r;
            if ((row >> 1) < vs)
                sT[(row >> 1) * 33 + (row & 1) * 16 + lm] = a3[r];
        }
    }
    __syncthreads();

    // ==== final MLP (32->16->16->2) + softmax, f32 weights ====
    if (tid < vs) {
        const float* tr = sT + tid * 33;
        float g1[16];
        #pragma unroll
        for (int o = 0; o < 16; ++o) g1[o] = f_b1[o];
        #pragma unroll
        for (int k = 0; k < 32; ++k) {
            const float hk = tr[k];
            const float* wr = f_w1 + k * 16;
            #pragma unroll
            for (int o = 0; o < 16; ++o) g1[o] = fmaf(hk, wr[o], g1[o]);
        }
        float g2[16];
        #pragma unroll
        for (int o = 0; o < 16; ++o) g2[o] = f_b2[o];
        #pragma unroll
        for (int k = 0; k < 16; ++k) {
            const float hk = fmaxf(g1[k], 0.f);
            const float* wr = f_w2 + k * 16;
            #pragma unroll
            for (int o = 0; o < 16; ++o) g2[o] = fmaf(hk, wr[o], g2[o]);
        }
        float l0 = f_b3[0], l1 = f_b3[1];
        #pragma unroll
        for (int k = 0; k < 16; ++k) {
            const float hk = fmaxf(g2[k], 0.f);
            l0 = fmaf(hk, f_w3[2 * k], l0);
            l1 = fmaf(hk, f_w3[2 * k + 1], l1);
        }
        const float e = expf(l1 - l0);
        const float p0 = 1.f / (1.f + e);
        out[(size_t)(s0 + tid) * 2]     = p0;
        out[(size_t)(s0 + tid) * 2 + 1] = 1.f - p0;
    }
}

extern "C" void kernel_launch(void* const* d_in, const int* in_sizes, int n_in,
                              void* d_out, int out_size, void* d_ws, size_t ws_size,
                              hipStream_t stream) {
    (void)in_sizes; (void)n_in; (void)out_size; (void)ws_size;
    const float* x    = (const float*)d_in[0];
    const float* h_w1 = (const float*)d_in[1];  const float* h_b1 = (const float*)d_in[2];
    const float* h_w2 = (const float*)d_in[3];  const float* h_b2 = (const float*)d_in[4];
    const float* h_w3 = (const float*)d_in[5];  const float* h_b3 = (const float*)d_in[6];
    const float* c_w1 = (const float*)d_in[7];  const float* c_b1 = (const float*)d_in[8];
    const float* c_w2 = (const float*)d_in[9];  const float* c_b2 = (const float*)d_in[10];
    const float* c_w3 = (const float*)d_in[11]; const float* c_b3 = (const float*)d_in[12];
    const float* t_w1 = (const float*)d_in[13]; const float* t_b1 = (const float*)d_in[14];
    const float* t_w2 = (const float*)d_in[15]; const float* t_b2 = (const float*)d_in[16];
    const float* t_w3 = (const float*)d_in[17]; const float* t_b3 = (const float*)d_in[18];
    const float* f_w1 = (const float*)d_in[19]; const float* f_b1 = (const float*)d_in[20];
    const float* f_w2 = (const float*)d_in[21]; const float* f_b2 = (const float*)d_in[22];
    const float* f_w3 = (const float*)d_in[23]; const float* f_b3 = (const float*)d_in[24];
    float* out = (float*)d_out;

    unsigned short* wb = (unsigned short*)d_ws;

    conv_weights<<<(OW_TOT + 255) / 256, 256, 0, stream>>>(
        h_w1, h_w2, h_w3, c_w1, c_w2, c_w3, t_w1, t_w2, t_w3, wb);

    const int grid = (NB + SPB - 1) / SPB;    // 2731
    fused_all<<<grid, 256, 0, stream>>>(
        x, wb,
        h_b1, h_b2, h_b3, c_b1, c_b2, c_b3, t_b1, t_b2, t_b3,
        f_w1, f_b1, f_w2, f_b2, f_w3, f_b3, out);
}